// Round 1
// baseline (626.687 us; speedup 1.0000x reference)
//
#include <hip/hip_runtime.h>

// Problem constants (fixed by setup_inputs): B=1, C=128, H=96, W=128
#define K_TOT 128      // channels
#define H_DIM 96
#define W_DIM 128
#define M_TOT (H_DIM * W_DIM)   // 12288 left pixels
#define N_TOT (H_DIM * W_DIM)   // 12288 right pixels
#define SCALE 4

#define BM 128
#define BN 128
#define KB 32          // K staged per LDS chunk

#define NEG_INF (-3.402823e38f)

// Main kernel: for an m-tile of 128 left pixels and an n-range (split s),
// compute all dots and keep running (max, argmax) per m.
__global__ __launch_bounds__(256, 4)
void corr_argmax_kernel(const float* __restrict__ L, const float* __restrict__ R,
                        float* __restrict__ pbest, int* __restrict__ pidx,
                        int nsplit) {
    __shared__ float As[KB][BM];   // 16 KB
    __shared__ float Bs[KB][BN];   // 16 KB

    const int tid = threadIdx.x;
    const int mtiles = M_TOT / BM;            // 96
    const int mt = blockIdx.x % mtiles;
    const int s  = blockIdx.x / mtiles;       // n-split id
    const int m0 = mt * BM;
    const int ns = N_TOT / nsplit;            // columns per split
    const int ntiles = ns / BN;
    const int tx = tid & 15;                  // n-group 0..15
    const int ty = tid >> 4;                  // m-group 0..15

    float rbest[8];
    int   ridx[8];
#pragma unroll
    for (int i = 0; i < 8; ++i) { rbest[i] = NEG_INF; ridx[i] = 0; }

    for (int nt = 0; nt < ntiles; ++nt) {
        const int n0 = s * ns + nt * BN;
        float acc[8][8];
#pragma unroll
        for (int i = 0; i < 8; ++i)
#pragma unroll
            for (int j = 0; j < 8; ++j) acc[i][j] = 0.f;

        for (int kb = 0; kb < K_TOT; kb += KB) {
            __syncthreads();   // protect LDS from previous iter's readers
            // Stage A and B chunks: each KB x 128 floats = 1024 float4s.
#pragma unroll
            for (int r = 0; r < 4; ++r) {
                int f  = tid + 256 * r;
                int kk = f >> 5;          // 32 float4 per 128-float row
                int c4 = f & 31;
                float4 va = *reinterpret_cast<const float4*>(
                    &L[(size_t)(kb + kk) * M_TOT + m0 + c4 * 4]);
                *reinterpret_cast<float4*>(&As[kk][c4 * 4]) = va;
                float4 vb = *reinterpret_cast<const float4*>(
                    &R[(size_t)(kb + kk) * N_TOT + n0 + c4 * 4]);
                *reinterpret_cast<float4*>(&Bs[kk][c4 * 4]) = vb;
            }
            __syncthreads();
#pragma unroll 4
            for (int kk = 0; kk < KB; ++kk) {
                float4 a0 = *reinterpret_cast<const float4*>(&As[kk][ty * 8]);
                float4 a1 = *reinterpret_cast<const float4*>(&As[kk][ty * 8 + 4]);
                float4 b0 = *reinterpret_cast<const float4*>(&Bs[kk][tx * 8]);
                float4 b1 = *reinterpret_cast<const float4*>(&Bs[kk][tx * 8 + 4]);
                float a[8] = {a0.x, a0.y, a0.z, a0.w, a1.x, a1.y, a1.z, a1.w};
                float b[8] = {b0.x, b0.y, b0.z, b0.w, b1.x, b1.y, b1.z, b1.w};
#pragma unroll
                for (int i = 0; i < 8; ++i)
#pragma unroll
                    for (int j = 0; j < 8; ++j)
                        acc[i][j] = fmaf(a[i], b[j], acc[i][j]);
            }
        }
        // Fold this tile into the running per-m best (n ascending => strict >
        // keeps the first occurrence, matching jnp.argmax).
#pragma unroll
        for (int i = 0; i < 8; ++i) {
#pragma unroll
            for (int j = 0; j < 8; ++j) {
                int n = n0 + tx * 8 + j;
                if (acc[i][j] > rbest[i]) { rbest[i] = acc[i][j]; ridx[i] = n; }
            }
        }
    }

    // Cross-thread reduce: 16 threads (tx=0..15) share each m row.
    __syncthreads();
    float (*redv)[BM] = reinterpret_cast<float(*)[BM]>(&As[0][0]); // 16x128 fits
    int   (*redi)[BM] = reinterpret_cast<int  (*)[BM]>(&Bs[0][0]);
#pragma unroll
    for (int i = 0; i < 8; ++i) {
        redv[tx][ty * 8 + i] = rbest[i];
        redi[tx][ty * 8 + i] = ridx[i];
    }
    __syncthreads();
    if (tid < BM) {
        float bv = NEG_INF; int bi = 0x7fffffff;
        for (int t = 0; t < 16; ++t) {
            float v  = redv[t][tid];
            int   ix = redi[t][tid];
            if (v > bv || (v == bv && ix < bi)) { bv = v; bi = ix; }
        }
        pbest[(size_t)s * M_TOT + m0 + tid] = bv;
        pidx [(size_t)s * M_TOT + m0 + tid] = bi;
    }
}

// Reduce over n-splits + decode argmax -> flow (u,v) and cost.
__global__ void finalize_kernel(const float* __restrict__ pbest,
                                const int* __restrict__ pidx,
                                float* __restrict__ out, int nsplit) {
    int m = blockIdx.x * blockDim.x + threadIdx.x;
    if (m >= M_TOT) return;
    float bv = NEG_INF; int bi = 0x7fffffff;
    for (int s = 0; s < nsplit; ++s) {
        float v  = pbest[(size_t)s * M_TOT + m];
        int   ix = pidx [(size_t)s * M_TOT + m];
        if (v > bv || (v == bv && ix < bi)) { bv = v; bi = ix; }
    }
    int h = m / W_DIM, w = m % W_DIM;
    int i = bi / W_DIM, j = bi % W_DIM;
    // u = -(j*scale_x - w), v = -(i*scale_y - h)
    out[m * 2 + 0] = (float)(w - SCALE * j);
    out[m * 2 + 1] = (float)(h - SCALE * i);
    out[2 * M_TOT + m] = bv;   // flow_cost after flow [H,W,2]
}

extern "C" void kernel_launch(void* const* d_in, const int* in_sizes, int n_in,
                              void* d_out, int out_size, void* d_ws, size_t ws_size,
                              hipStream_t stream) {
    const float* L = (const float*)d_in[0];
    const float* R = (const float*)d_in[1];
    float* out = (float*)d_out;

    // Workspace: per-split partial (best, idx). 8 splits need 768 KB.
    int nsplit = 8;
    while (nsplit > 1 && (size_t)nsplit * M_TOT * 8 > ws_size) nsplit >>= 1;

    float* pbest = (float*)d_ws;
    int*   pidx  = (int*)((char*)d_ws + (size_t)nsplit * M_TOT * sizeof(float));

    dim3 grid((M_TOT / BM) * nsplit);   // 96 * nsplit
    corr_argmax_kernel<<<grid, dim3(256), 0, stream>>>(L, R, pbest, pidx, nsplit);
    finalize_kernel<<<dim3((M_TOT + 255) / 256), dim3(256), 0, stream>>>(pbest, pidx, out, nsplit);
}

// Round 2
// 506.713 us; speedup vs baseline: 1.2368x; 1.2368x over previous
//
#include <hip/hip_runtime.h>

// Problem constants (fixed by setup_inputs): B=1, C=128, H=96, W=128
#define K_TOT 128      // channels
#define H_DIM 96
#define W_DIM 128
#define M_TOT (H_DIM * W_DIM)   // 12288 left pixels
#define N_TOT (H_DIM * W_DIM)   // 12288 right pixels
#define SCALE 4

#define BM 128
#define BN 128
#define KB 32          // K staged per LDS chunk

#define NEG_INF (-3.402823e38f)

// Main kernel: for an m-tile of 128 left pixels and an n-range (split s),
// compute all dots and keep running (max, argmax) per m.
// Micro-tile mapping: thread (tx,ty) owns rows {ty*4+ii + ih*64} and
// cols {tx*4+jj + jh*64} — 16B LDS reads at stride 16B => max 2-way bank
// aliasing (free), vs the old tx*8 mapping's 4-way conflict.
__global__ __launch_bounds__(256)
void corr_argmax_kernel(const float* __restrict__ L, const float* __restrict__ R,
                        float* __restrict__ pbest, int* __restrict__ pidx,
                        int nsplit) {
    __shared__ float As[KB][BM];   // 16 KB
    __shared__ float Bs[KB][BN];   // 16 KB

    const int tid = threadIdx.x;
    const int mtiles = M_TOT / BM;            // 96
    const int mt = blockIdx.x % mtiles;
    const int s  = blockIdx.x / mtiles;       // n-split id
    const int m0 = mt * BM;
    const int ns = N_TOT / nsplit;            // columns per split
    const int ntiles = ns / BN;
    const int tx = tid & 15;                  // n-group 0..15
    const int ty = tid >> 4;                  // m-group 0..15

    float rbest[8];
    int   ridx[8];
#pragma unroll
    for (int i = 0; i < 8; ++i) { rbest[i] = NEG_INF; ridx[i] = 0; }

    for (int nt = 0; nt < ntiles; ++nt) {
        const int n0 = s * ns + nt * BN;
        float acc[8][8];
#pragma unroll
        for (int i = 0; i < 8; ++i)
#pragma unroll
            for (int j = 0; j < 8; ++j) acc[i][j] = 0.f;

        for (int kb = 0; kb < K_TOT; kb += KB) {
            __syncthreads();   // protect LDS from previous iter's readers
            // Stage A and B chunks: each KB x 128 floats = 1024 float4s.
#pragma unroll
            for (int r = 0; r < 4; ++r) {
                int f  = tid + 256 * r;
                int kk = f >> 5;          // 32 float4 per 128-float row
                int c4 = f & 31;
                float4 va = *reinterpret_cast<const float4*>(
                    &L[(size_t)(kb + kk) * M_TOT + m0 + c4 * 4]);
                *reinterpret_cast<float4*>(&As[kk][c4 * 4]) = va;
                float4 vb = *reinterpret_cast<const float4*>(
                    &R[(size_t)(kb + kk) * N_TOT + n0 + c4 * 4]);
                *reinterpret_cast<float4*>(&Bs[kk][c4 * 4]) = vb;
            }
            __syncthreads();
#pragma unroll 4
            for (int kk = 0; kk < KB; ++kk) {
                float4 a0 = *reinterpret_cast<const float4*>(&As[kk][ty * 4]);
                float4 a1 = *reinterpret_cast<const float4*>(&As[kk][64 + ty * 4]);
                float4 b0 = *reinterpret_cast<const float4*>(&Bs[kk][tx * 4]);
                float4 b1 = *reinterpret_cast<const float4*>(&Bs[kk][64 + tx * 4]);
                float a[8] = {a0.x, a0.y, a0.z, a0.w, a1.x, a1.y, a1.z, a1.w};
                float b[8] = {b0.x, b0.y, b0.z, b0.w, b1.x, b1.y, b1.z, b1.w};
#pragma unroll
                for (int i = 0; i < 8; ++i)
#pragma unroll
                    for (int j = 0; j < 8; ++j)
                        acc[i][j] = fmaf(a[i], b[j], acc[i][j]);
            }
        }
        // Fold this tile into the running per-m best, visiting j in globally
        // ascending n order (jh outer) => strict > keeps first occurrence.
#pragma unroll
        for (int i = 0; i < 8; ++i) {
#pragma unroll
            for (int jh = 0; jh < 2; ++jh)
#pragma unroll
            for (int jj = 0; jj < 4; ++jj) {
                int n = n0 + jh * 64 + tx * 4 + jj;
                float v = acc[i][jh * 4 + jj];
                if (v > rbest[i]) { rbest[i] = v; ridx[i] = n; }
            }
        }
    }

    // Cross-thread reduce: 16 threads (tx=0..15) share each m row.
    __syncthreads();
    float (*redv)[BM] = reinterpret_cast<float(*)[BM]>(&As[0][0]); // 16x128 fits
    int   (*redi)[BM] = reinterpret_cast<int  (*)[BM]>(&Bs[0][0]);
#pragma unroll
    for (int i = 0; i < 8; ++i) {
        int row = (i >> 2) * 64 + ty * 4 + (i & 3);
        redv[tx][row] = rbest[i];
        redi[tx][row] = ridx[i];
    }
    __syncthreads();
    if (tid < BM) {
        float bv = NEG_INF; int bi = 0x7fffffff;
        for (int t = 0; t < 16; ++t) {
            float v  = redv[t][tid];
            int   ix = redi[t][tid];
            if (v > bv || (v == bv && ix < bi)) { bv = v; bi = ix; }
        }
        pbest[(size_t)s * M_TOT + m0 + tid] = bv;
        pidx [(size_t)s * M_TOT + m0 + tid] = bi;
    }
}

// Reduce over n-splits + decode argmax -> flow (u,v) and cost.
__global__ void finalize_kernel(const float* __restrict__ pbest,
                                const int* __restrict__ pidx,
                                float* __restrict__ out, int nsplit) {
    int m = blockIdx.x * blockDim.x + threadIdx.x;
    if (m >= M_TOT) return;
    float bv = NEG_INF; int bi = 0x7fffffff;
    for (int s = 0; s < nsplit; ++s) {
        float v  = pbest[(size_t)s * M_TOT + m];
        int   ix = pidx [(size_t)s * M_TOT + m];
        if (v > bv || (v == bv && ix < bi)) { bv = v; bi = ix; }
    }
    int h = m / W_DIM, w = m % W_DIM;
    int i = bi / W_DIM, j = bi % W_DIM;
    // u = -(j*scale_x - w), v = -(i*scale_y - h)
    out[m * 2 + 0] = (float)(w - SCALE * j);
    out[m * 2 + 1] = (float)(h - SCALE * i);
    out[2 * M_TOT + m] = bv;   // flow_cost after flow [H,W,2]
}

extern "C" void kernel_launch(void* const* d_in, const int* in_sizes, int n_in,
                              void* d_out, int out_size, void* d_ws, size_t ws_size,
                              hipStream_t stream) {
    const float* L = (const float*)d_in[0];
    const float* R = (const float*)d_in[1];
    float* out = (float*)d_out;

    // Workspace: per-split partial (best, idx). 8 splits need 768 KB.
    int nsplit = 8;
    while (nsplit > 1 && (size_t)nsplit * M_TOT * 8 > ws_size) nsplit >>= 1;

    float* pbest = (float*)d_ws;
    int*   pidx  = (int*)((char*)d_ws + (size_t)nsplit * M_TOT * sizeof(float));

    dim3 grid((M_TOT / BM) * nsplit);   // 96 * nsplit
    corr_argmax_kernel<<<grid, dim3(256), 0, stream>>>(L, R, pbest, pidx, nsplit);
    finalize_kernel<<<dim3((M_TOT + 255) / 256), dim3(256), 0, stream>>>(pbest, pidx, out, nsplit);
}

// Round 3
// 461.153 us; speedup vs baseline: 1.3590x; 1.0988x over previous
//
#include <hip/hip_runtime.h>

// Problem constants (fixed by setup_inputs): B=1, C=128, H=96, W=128
#define K_TOT 128
#define H_DIM 96
#define W_DIM 128
#define M_TOT (H_DIM * W_DIM)   // 12288
#define N_TOT (H_DIM * W_DIM)   // 12288
#define SCALE 4
#define NEG_INF (-3.402823e38f)

typedef _Float16 f16x8 __attribute__((ext_vector_type(8)));
typedef float f32x4 __attribute__((ext_vector_type(4)));

// async global->LDS, 16B per lane; LDS dest is wave-uniform base + lane*16
#define ASYNC16(lds_ptr, g_ptr) \
  __builtin_amdgcn_global_load_lds( \
      (const __attribute__((address_space(1))) unsigned int*)(g_ptr), \
      (__attribute__((address_space(3))) unsigned int*)(lds_ptr), 16, 0, 0)

// ---------------------------------------------------------------------------
// Prep: split fp32 [K][P] into f16 hi/lo-scaled pair, transposed to [P][K].
// x = h + l/4096, h = f16(x), l = f16((x-h)*4096)  (l never meaningfully
// subnormal => MFMA denorm behavior irrelevant; dropped l*l' ~ 2^-24|xy|).
// ---------------------------------------------------------------------------
__global__ __launch_bounds__(256)
void split_transpose_kernel(const float* __restrict__ L, const float* __restrict__ R,
                            _Float16* __restrict__ Lh, _Float16* __restrict__ Ll,
                            _Float16* __restrict__ Rh, _Float16* __restrict__ Rl) {
    __shared__ __align__(16) _Float16 Th[64][128];
    __shared__ __align__(16) _Float16 Tl[64][128];
    const int t = threadIdx.x;
    const int isR = blockIdx.x >= 192;
    const int P0 = (blockIdx.x - (isR ? 192 : 0)) * 64;
    const float* src = isR ? R : L;
    _Float16* dh = isR ? Rh : Lh;
    _Float16* dl = isR ? Rl : Ll;
    const int p4 = (t & 15) * 4;
    const int k0 = t >> 4;
#pragma unroll
    for (int it = 0; it < 8; ++it) {
        const int k = k0 + it * 16;
        float4 v = *(const float4*)&src[(size_t)k * M_TOT + P0 + p4];
        float xs[4] = {v.x, v.y, v.z, v.w};
#pragma unroll
        for (int j = 0; j < 4; ++j) {
            _Float16 h = (_Float16)xs[j];
            float r = xs[j] - (float)h;        // exact (Sterbenz)
            _Float16 l = (_Float16)(r * 4096.0f);
            Th[p4 + j][k] = h;
            Tl[p4 + j][k] = l;
        }
    }
    __syncthreads();
    const unsigned* sh = (const unsigned*)&Th[0][0];
    const unsigned* sl = (const unsigned*)&Tl[0][0];
    unsigned* oh = (unsigned*)dh;
    unsigned* ol = (unsigned*)dl;
    const int cd = t & 63;
    const int r0 = t >> 6;
#pragma unroll
    for (int pass = 0; pass < 16; ++pass) {
        const int row = pass * 4 + r0;
        oh[(size_t)(P0 + row) * 64 + cd] = sh[row * 64 + cd];
        ol[(size_t)(P0 + row) * 64 + cd] = sl[row * 64 + cd];
    }
}

// ---------------------------------------------------------------------------
// Main: 128x128 tile per block, 4 waves of 64x64, mfma_f32_16x16x32_f16.
// corr[m][n] = sum_k Lh+Ll/4096 dot Rh+Rl/4096:
//   acc1 += Ah*Bh ; acc2 += Ah*Bl + Al*Bh ; val = acc1 + acc2/4096.
// LDS planes [row][slot] with slot = ko ^ ((row>>1)&3) XOR-swizzle
// (source-pre-swizzled for global_load_lds; same XOR on frag read) =>
// frag ds_read_b128 is 2-way bank aliasing only (free).
// ---------------------------------------------------------------------------
__global__ __launch_bounds__(256)
void mfma_corr_kernel(const _Float16* __restrict__ Lh, const _Float16* __restrict__ Ll,
                      const _Float16* __restrict__ Rh, const _Float16* __restrict__ Rl,
                      float* __restrict__ pbest, int* __restrict__ pidx) {
    __shared__ __align__(16) _Float16 planes[4][128 * 32];  // Ah, Al, Bh, Bl (8KB each)
    __shared__ float redv[2][128];
    __shared__ int   redi[2][128];

    const int tid  = threadIdx.x;
    const int lane = tid & 63;
    const int wid  = tid >> 6;     // 0..3
    const int wr   = wid >> 1;     // m half
    const int wc   = wid & 1;      // n half
    const int mt   = blockIdx.x % (M_TOT / 128);
    const int nt   = blockIdx.x / (M_TOT / 128);
    const int m0   = mt * 128;
    const int n0   = nt * 128;

    const _Float16* gsrc[4] = { Lh + (size_t)m0 * K_TOT, Ll + (size_t)m0 * K_TOT,
                                Rh + (size_t)n0 * K_TOT, Rl + (size_t)n0 * K_TOT };

    f32x4 acc1[4][4];
    f32x4 acc2[4][4];
#pragma unroll
    for (int i = 0; i < 4; ++i)
#pragma unroll
        for (int j = 0; j < 4; ++j) {
            acc1[i][j] = (f32x4)(0.0f);
            acc2[i][j] = (f32x4)(0.0f);
        }

    const int lrow4 = lane >> 2;   // row within 16-row segment
    const int lslot = lane & 3;    // physical 16B slot
    const int fr = lane & 15;
    const int fg = lane >> 4;      // k-group

    for (int kb = 0; kb < K_TOT; kb += 32) {
        __syncthreads();           // previous chunk's reads complete
#pragma unroll
        for (int pl = 0; pl < 4; ++pl) {
#pragma unroll
            for (int half = 0; half < 2; ++half) {
                const int sg = wid + 4 * half;          // segment 0..7 (16 rows)
                const int m  = sg * 16 + lrow4;
                const int ko = lslot ^ ((m >> 1) & 3);  // pre-swizzled source
                ASYNC16((char*)&planes[pl][0] + sg * 1024,
                        gsrc[pl] + (size_t)m * K_TOT + kb + ko * 8);
            }
        }
        __syncthreads();           // drains vmcnt -> staged data visible

        f16x8 ah[4], al[4], bh[4], bl[4];
#pragma unroll
        for (int mi = 0; mi < 4; ++mi) {
            const int row  = wr * 64 + mi * 16 + fr;
            const int slot = fg ^ ((row >> 1) & 3);
            ah[mi] = *(const f16x8*)((const char*)&planes[0][0] + row * 64 + slot * 16);
            al[mi] = *(const f16x8*)((const char*)&planes[1][0] + row * 64 + slot * 16);
        }
#pragma unroll
        for (int ni = 0; ni < 4; ++ni) {
            const int row  = wc * 64 + ni * 16 + fr;
            const int slot = fg ^ ((row >> 1) & 3);
            bh[ni] = *(const f16x8*)((const char*)&planes[2][0] + row * 64 + slot * 16);
            bl[ni] = *(const f16x8*)((const char*)&planes[3][0] + row * 64 + slot * 16);
        }
#pragma unroll
        for (int mi = 0; mi < 4; ++mi)
#pragma unroll
            for (int ni = 0; ni < 4; ++ni) {
                acc1[mi][ni] = __builtin_amdgcn_mfma_f32_16x16x32_f16(ah[mi], bh[ni], acc1[mi][ni], 0, 0, 0);
                acc2[mi][ni] = __builtin_amdgcn_mfma_f32_16x16x32_f16(ah[mi], bl[ni], acc2[mi][ni], 0, 0, 0);
                acc2[mi][ni] = __builtin_amdgcn_mfma_f32_16x16x32_f16(al[mi], bh[ni], acc2[mi][ni], 0, 0, 0);
            }
    }

    // --- epilogue: per-m argmax over this block's 128 n ---
    // C layout: col n = fr, row m = fg*4 + r (within 16x16 frag).
    float rb[16]; int ri[16];
    const float s2 = 1.0f / 4096.0f;
#pragma unroll
    for (int mi = 0; mi < 4; ++mi)
#pragma unroll
        for (int r = 0; r < 4; ++r) {
            const int e = mi * 4 + r;
            float best = NEG_INF; int besti = 0x7fffffff;
#pragma unroll
            for (int ni = 0; ni < 4; ++ni) {   // ni ascending = n ascending
                float v = acc1[mi][ni][r] + acc2[mi][ni][r] * s2;
                int n = n0 + wc * 64 + ni * 16 + fr;
                if (v > best) { best = v; besti = n; }
            }
            rb[e] = best; ri[e] = besti;
        }
    // 16-lane group reduce (lanes share fg => same m rows, different n)
#pragma unroll
    for (int d = 1; d < 16; d <<= 1) {
#pragma unroll
        for (int e = 0; e < 16; ++e) {
            float ov = __shfl_xor(rb[e], d, 64);
            int   oi = __shfl_xor(ri[e], d, 64);
            if (ov > rb[e] || (ov == rb[e] && oi < ri[e])) { rb[e] = ov; ri[e] = oi; }
        }
    }
    // lane fr==e publishes entry e (compile-time index per rule #20)
#pragma unroll
    for (int e = 0; e < 16; ++e) {
        if (fr == e) {
            const int m_local = wr * 64 + (e >> 2) * 16 + fg * 4 + (e & 3);
            redv[wc][m_local] = rb[e];
            redi[wc][m_local] = ri[e];
        }
    }
    __syncthreads();
    if (tid < 128) {
        float bv = redv[0][tid]; int bi = redi[0][tid];
        float v  = redv[1][tid]; int ix = redi[1][tid];
        if (v > bv || (v == bv && ix < bi)) { bv = v; bi = ix; }
        pbest[(size_t)nt * M_TOT + m0 + tid] = bv;
        pidx [(size_t)nt * M_TOT + m0 + tid] = bi;
    }
}

// ---------------------------------------------------------------------------
// Fallback fp32 VALU path (round-2 kernel) in case ws_size is too small.
// ---------------------------------------------------------------------------
#define BM 128
#define BN 128
#define KB 32
__global__ __launch_bounds__(256)
void corr_argmax_kernel(const float* __restrict__ L, const float* __restrict__ R,
                        float* __restrict__ pbest, int* __restrict__ pidx,
                        int nsplit) {
    __shared__ float As[KB][BM];
    __shared__ float Bs[KB][BN];
    const int tid = threadIdx.x;
    const int mtiles = M_TOT / BM;
    const int mt = blockIdx.x % mtiles;
    const int s  = blockIdx.x / mtiles;
    const int m0 = mt * BM;
    const int ns = N_TOT / nsplit;
    const int ntiles = ns / BN;
    const int tx = tid & 15;
    const int ty = tid >> 4;
    float rbest[8]; int ridx[8];
#pragma unroll
    for (int i = 0; i < 8; ++i) { rbest[i] = NEG_INF; ridx[i] = 0; }
    for (int nt = 0; nt < ntiles; ++nt) {
        const int n0 = s * ns + nt * BN;
        float acc[8][8];
#pragma unroll
        for (int i = 0; i < 8; ++i)
#pragma unroll
            for (int j = 0; j < 8; ++j) acc[i][j] = 0.f;
        for (int kb = 0; kb < K_TOT; kb += KB) {
            __syncthreads();
#pragma unroll
            for (int r = 0; r < 4; ++r) {
                int f  = tid + 256 * r;
                int kk = f >> 5;
                int c4 = f & 31;
                float4 va = *reinterpret_cast<const float4*>(&L[(size_t)(kb + kk) * M_TOT + m0 + c4 * 4]);
                *reinterpret_cast<float4*>(&As[kk][c4 * 4]) = va;
                float4 vb = *reinterpret_cast<const float4*>(&R[(size_t)(kb + kk) * N_TOT + n0 + c4 * 4]);
                *reinterpret_cast<float4*>(&Bs[kk][c4 * 4]) = vb;
            }
            __syncthreads();
#pragma unroll 4
            for (int kk = 0; kk < KB; ++kk) {
                float4 a0 = *reinterpret_cast<const float4*>(&As[kk][ty * 4]);
                float4 a1 = *reinterpret_cast<const float4*>(&As[kk][64 + ty * 4]);
                float4 b0 = *reinterpret_cast<const float4*>(&Bs[kk][tx * 4]);
                float4 b1 = *reinterpret_cast<const float4*>(&Bs[kk][64 + tx * 4]);
                float a[8] = {a0.x, a0.y, a0.z, a0.w, a1.x, a1.y, a1.z, a1.w};
                float b[8] = {b0.x, b0.y, b0.z, b0.w, b1.x, b1.y, b1.z, b1.w};
#pragma unroll
                for (int i = 0; i < 8; ++i)
#pragma unroll
                    for (int j = 0; j < 8; ++j)
                        acc[i][j] = fmaf(a[i], b[j], acc[i][j]);
            }
        }
#pragma unroll
        for (int i = 0; i < 8; ++i)
#pragma unroll
            for (int jh = 0; jh < 2; ++jh)
#pragma unroll
                for (int jj = 0; jj < 4; ++jj) {
                    int n = n0 + jh * 64 + tx * 4 + jj;
                    float v = acc[i][jh * 4 + jj];
                    if (v > rbest[i]) { rbest[i] = v; ridx[i] = n; }
                }
    }
    __syncthreads();
    float (*redv)[BM] = reinterpret_cast<float(*)[BM]>(&As[0][0]);
    int   (*redi)[BM] = reinterpret_cast<int  (*)[BM]>(&Bs[0][0]);
#pragma unroll
    for (int i = 0; i < 8; ++i) {
        int row = (i >> 2) * 64 + ty * 4 + (i & 3);
        redv[tx][row] = rbest[i];
        redi[tx][row] = ridx[i];
    }
    __syncthreads();
    if (tid < BM) {
        float bv = NEG_INF; int bi = 0x7fffffff;
        for (int t = 0; t < 16; ++t) {
            float v  = redv[t][tid];
            int   ix = redi[t][tid];
            if (v > bv || (v == bv && ix < bi)) { bv = v; bi = ix; }
        }
        pbest[(size_t)s * M_TOT + m0 + tid] = bv;
        pidx [(size_t)s * M_TOT + m0 + tid] = bi;
    }
}

// Reduce over n-splits + decode argmax -> flow (u,v) and cost.
__global__ void finalize_kernel(const float* __restrict__ pbest,
                                const int* __restrict__ pidx,
                                float* __restrict__ out, int nsplit) {
    int m = blockIdx.x * blockDim.x + threadIdx.x;
    if (m >= M_TOT) return;
    float bv = NEG_INF; int bi = 0x7fffffff;
    for (int s = 0; s < nsplit; ++s) {
        float v  = pbest[(size_t)s * M_TOT + m];
        int   ix = pidx [(size_t)s * M_TOT + m];
        if (v > bv || (v == bv && ix < bi)) { bv = v; bi = ix; }
    }
    int h = m / W_DIM, w = m % W_DIM;
    int i = bi / W_DIM, j = bi % W_DIM;
    out[m * 2 + 0] = (float)(w - SCALE * j);
    out[m * 2 + 1] = (float)(h - SCALE * i);
    out[2 * M_TOT + m] = bv;
}

extern "C" void kernel_launch(void* const* d_in, const int* in_sizes, int n_in,
                              void* d_out, int out_size, void* d_ws, size_t ws_size,
                              hipStream_t stream) {
    const float* L = (const float*)d_in[0];
    const float* R = (const float*)d_in[1];
    float* out = (float*)d_out;

    const size_t PK = (size_t)M_TOT * K_TOT;                 // 1.57M elems
    const size_t need = 4 * PK * sizeof(_Float16) + (size_t)96 * M_TOT * 8;
    if (ws_size >= need) {
        _Float16* Lh = (_Float16*)d_ws;
        _Float16* Ll = Lh + PK;
        _Float16* Rh = Ll + PK;
        _Float16* Rl = Rh + PK;
        float* pbest = (float*)(Rl + PK);
        int*   pidx  = (int*)(pbest + (size_t)96 * M_TOT);
        split_transpose_kernel<<<dim3(384), dim3(256), 0, stream>>>(L, R, Lh, Ll, Rh, Rl);
        mfma_corr_kernel<<<dim3(96 * 96), dim3(256), 0, stream>>>(Lh, Ll, Rh, Rl, pbest, pidx);
        finalize_kernel<<<dim3(48), dim3(256), 0, stream>>>(pbest, pidx, out, 96);
    } else {
        int nsplit = 8;
        while (nsplit > 1 && (size_t)nsplit * M_TOT * 8 > ws_size) nsplit >>= 1;
        float* pbest = (float*)d_ws;
        int*   pidx  = (int*)((char*)d_ws + (size_t)nsplit * M_TOT * sizeof(float));
        corr_argmax_kernel<<<dim3((M_TOT / BM) * nsplit), dim3(256), 0, stream>>>(L, R, pbest, pidx, nsplit);
        finalize_kernel<<<dim3((M_TOT + 255) / 256), dim3(256), 0, stream>>>(pbest, pidx, out, nsplit);
    }
}

// Round 4
// 281.990 us; speedup vs baseline: 2.2224x; 1.6354x over previous
//
#include <hip/hip_runtime.h>

// Problem constants: B=1, C=128, H=96, W=128
#define K_TOT 128
#define H_DIM 96
#define W_DIM 128
#define M_TOT (H_DIM * W_DIM)   // 12288
#define N_TOT (H_DIM * W_DIM)   // 12288
#define SCALE 4
#define NEG_INF (-3.402823e38f)

#define KP 384                  // folded K' = 3 x 128 sections
#define NCH 12                  // K' chunks of 32

typedef _Float16 f16x8 __attribute__((ext_vector_type(8)));
typedef float f32x16 __attribute__((ext_vector_type(16)));

// async global->LDS, 16B/lane; LDS dest = wave-uniform base + lane*16
#define ASYNC16(lds_ptr, g_ptr) \
  __builtin_amdgcn_global_load_lds( \
      (const __attribute__((address_space(1))) unsigned int*)(g_ptr), \
      (__attribute__((address_space(3))) unsigned int*)(lds_ptr), 16, 0, 0)

// ---------------------------------------------------------------------------
// Prep: fp32 [K][P] -> f16 triplet rows [P][384].
//  x = h + l/64 with h=f16(x), l=f16((x-hf)*64)  (x-hf exact by Sterbenz)
//  L rows: [h | h/64 | l]   R rows: [h | l | h/64]
//  => dot(A',B') = h*h' + h*(y-h') + (x-h)*h'  (drop (x-h)(y-h') ~ 2^-22|xy|)
// ---------------------------------------------------------------------------
__global__ __launch_bounds__(256)
void split_prep_kernel(const float* __restrict__ L, const float* __restrict__ R,
                       _Float16* __restrict__ Ls, _Float16* __restrict__ Rs) {
    __shared__ __align__(16) _Float16 T[3][64][136];   // planes: 0=h, 1=l, 2=h/64
    const int t = threadIdx.x;
    const int isR = blockIdx.x >= 192;
    const int P0 = (blockIdx.x - (isR ? 192 : 0)) * 64;
    const float* src = isR ? R : L;
    _Float16* dst = isR ? Rs : Ls;

    const int p4 = (t & 15) * 4;
    const int k0 = t >> 4;
#pragma unroll
    for (int it = 0; it < 8; ++it) {
        const int k = k0 + it * 16;
        float4 v = *(const float4*)&src[(size_t)k * M_TOT + P0 + p4];
        float xs[4] = {v.x, v.y, v.z, v.w};
#pragma unroll
        for (int j = 0; j < 4; ++j) {
            _Float16 h = (_Float16)xs[j];
            float hf = (float)h;
            float r = xs[j] - hf;                    // exact
            T[0][p4 + j][k] = h;
            T[1][p4 + j][k] = (_Float16)(r * 64.0f);
            T[2][p4 + j][k] = (_Float16)(hf * 0.015625f);  // h/64 (exact exp shift)
        }
    }
    __syncthreads();
    // write out: 64 rows x 48 chunks of 16B (8 f16). sec0=h, then per-side order.
#pragma unroll
    for (int it = 0; it < 12; ++it) {
        const int cid = it * 256 + t;
        const int row = cid / 48;
        const int seg = cid % 48;
        const int sec = seg >> 4;       // 0,1,2
        const int sub = seg & 15;
        const int plane = (sec == 0) ? 0 : (isR ? sec : 3 - sec);
        float4 v = *(const float4*)&T[plane][row][sub * 8];
        *(float4*)&dst[(size_t)(P0 + row) * KP + seg * 8] = v;
    }
}

// init keys to 0 (below any real packed key)
__global__ void init_keys_kernel(unsigned long long* __restrict__ keys) {
    int m = blockIdx.x * blockDim.x + threadIdx.x;
    if (m < M_TOT) keys[m] = 0ull;
}

// ---------------------------------------------------------------------------
// Main: 128x256 tile per 4-wave block; wave-tile 64x128; mfma_f32_32x32x16_f16;
// K'=384 in 12 chunks of 32, double-buffered LDS with 1 barrier per chunk.
// LDS layout per buffer: rows of 64B = 4 x 16B slots, slot XOR-swizzled by
// ((row>>1)&3); staging pre-swizzles the per-lane GLOBAL source (rule #21).
// Argmax folded via packed u64 key = (ordered_float(v)<<32)|~n, atomicMax.
// ---------------------------------------------------------------------------
__global__ __launch_bounds__(256, 2)
void mfma_corr_kernel(const _Float16* __restrict__ Ls, const _Float16* __restrict__ Rs,
                      unsigned long long* __restrict__ keys) {
    __shared__ __align__(16) _Float16 As[2][128 * 32];   // 8KB per buffer
    __shared__ __align__(16) _Float16 Bs[2][256 * 32];   // 16KB per buffer

    const int tid  = threadIdx.x;
    const int lane = tid & 63;
    const int wid  = tid >> 6;      // 0..3
    const int wr   = wid >> 1;      // 0..1 : M 64-row slab
    const int wc   = wid & 1;       // 0..1 : N 128-col slab
    const int mt   = blockIdx.x % (M_TOT / 128);
    const int nt   = blockIdx.x / (M_TOT / 128);
    const int m0   = mt * 128;
    const int n0   = nt * 256;

    f32x16 acc[2][4];
#pragma unroll
    for (int mi = 0; mi < 2; ++mi)
#pragma unroll
        for (int ni = 0; ni < 4; ++ni) acc[mi][ni] = (f32x16)(0.0f);

    const int lr4  = lane >> 2;     // row within 16-row segment
    const int lsl  = lane & 3;      // physical slot
    const int col  = lane & 31;     // MFMA row/col lane index
    const int hi   = lane >> 5;     // k-half

    // stage one 32-f16 chunk of A(128 rows)+B(256 rows): 24 segs, 6 per wave
    auto stage = [&](int buf, int ch) {
#pragma unroll
        for (int i = 0; i < 6; ++i) {
            const int s  = wid * 6 + i;
            const int rl = (s < 8 ? s : s - 8) * 16 + lr4;
            const int ko = lsl ^ ((rl >> 1) & 3);       // pre-swizzled source slot
            if (s < 8) {
                ASYNC16((char*)&As[buf][0] + s * 1024,
                        Ls + (size_t)(m0 + rl) * KP + ch * 32 + ko * 8);
            } else {
                ASYNC16((char*)&Bs[buf][0] + (s - 8) * 1024,
                        Rs + (size_t)(n0 + rl) * KP + ch * 32 + ko * 8);
            }
        }
    };

    stage(0, 0);
    __syncthreads();
    int cur = 0;
    for (int ch = 0; ch < NCH; ++ch) {
        if (ch + 1 < NCH) stage(cur ^ 1, ch + 1);   // prefetch next chunk
#pragma unroll
        for (int kk = 0; kk < 2; ++kk) {            // two K=16 halves of the chunk
            f16x8 a[2], b[4];
#pragma unroll
            for (int mi = 0; mi < 2; ++mi) {
                const int rl = wr * 64 + mi * 32 + col;
                const int sl = (kk * 2 + hi) ^ ((rl >> 1) & 3);
                a[mi] = *(const f16x8*)((const char*)&As[cur][0] + rl * 64 + sl * 16);
            }
#pragma unroll
            for (int ni = 0; ni < 4; ++ni) {
                const int rl = wc * 128 + ni * 32 + col;
                const int sl = (kk * 2 + hi) ^ ((rl >> 1) & 3);
                b[ni] = *(const f16x8*)((const char*)&Bs[cur][0] + rl * 64 + sl * 16);
            }
#pragma unroll
            for (int mi = 0; mi < 2; ++mi)
#pragma unroll
                for (int ni = 0; ni < 4; ++ni)
                    acc[mi][ni] = __builtin_amdgcn_mfma_f32_32x32x16_f16(
                        a[mi], b[ni], acc[mi][ni], 0, 0, 0);
        }
        __syncthreads();   // drains vmcnt(0): next buffer staged; LDS reads done
        cur ^= 1;
    }

    // --- epilogue ---
    // C/D 32x32 layout: col = lane&31, row = (reg&3) + 8*(reg>>2) + 4*(lane>>5)
#pragma unroll
    for (int mi = 0; mi < 2; ++mi) {
#pragma unroll
        for (int reg = 0; reg < 16; ++reg) {
            float best = acc[mi][0][reg];
            int bni = 0;
#pragma unroll
            for (int ni = 1; ni < 4; ++ni) {    // ascending n => first-occurrence
                if (acc[mi][ni][reg] > best) { best = acc[mi][ni][reg]; bni = ni; }
            }
            const int n = n0 + wc * 128 + bni * 32 + col;
            unsigned vb = __float_as_uint(best);
            vb = (vb & 0x80000000u) ? ~vb : (vb | 0x80000000u);
            unsigned long long key =
                ((unsigned long long)vb << 32) | (unsigned)(~n);
#pragma unroll
            for (int d = 1; d < 32; d <<= 1) {  // reduce 32 lanes sharing this m
                unsigned long long o = __shfl_xor(key, d, 64);
                if (o > key) key = o;
            }
            if (col == 0) {
                const int m = m0 + wr * 64 + mi * 32 + (reg & 3) + 8 * (reg >> 2) + 4 * hi;
                atomicMax(&keys[m], key);
            }
        }
    }
}

// decode keys -> flow + cost
__global__ void finalize_keys_kernel(const unsigned long long* __restrict__ keys,
                                     float* __restrict__ out) {
    int m = blockIdx.x * blockDim.x + threadIdx.x;
    if (m >= M_TOT) return;
    unsigned long long key = keys[m];
    unsigned hi = (unsigned)(key >> 32);
    unsigned bits = (hi & 0x80000000u) ? (hi & 0x7fffffffu) : ~hi;
    float v = __uint_as_float(bits);
    int idx = (int)(~(unsigned)(key & 0xffffffffu));
    int h = m / W_DIM, w = m % W_DIM;
    int i = idx / W_DIM, j = idx % W_DIM;
    out[m * 2 + 0] = (float)(w - SCALE * j);
    out[m * 2 + 1] = (float)(h - SCALE * i);
    out[2 * M_TOT + m] = v;
}

// ---------------------------------------------------------------------------
// Fallback fp32 VALU path (round-2 kernel) in case ws_size is too small.
// ---------------------------------------------------------------------------
#define BM 128
#define BN 128
#define KB 32
__global__ __launch_bounds__(256)
void corr_argmax_kernel(const float* __restrict__ L, const float* __restrict__ R,
                        float* __restrict__ pbest, int* __restrict__ pidx,
                        int nsplit) {
    __shared__ float As[KB][BM];
    __shared__ float Bs[KB][BN];
    const int tid = threadIdx.x;
    const int mtiles = M_TOT / BM;
    const int mt = blockIdx.x % mtiles;
    const int s  = blockIdx.x / mtiles;
    const int m0 = mt * BM;
    const int ns = N_TOT / nsplit;
    const int ntiles = ns / BN;
    const int tx = tid & 15;
    const int ty = tid >> 4;
    float rbest[8]; int ridx[8];
#pragma unroll
    for (int i = 0; i < 8; ++i) { rbest[i] = NEG_INF; ridx[i] = 0; }
    for (int nt = 0; nt < ntiles; ++nt) {
        const int n0 = s * ns + nt * BN;
        float acc[8][8];
#pragma unroll
        for (int i = 0; i < 8; ++i)
#pragma unroll
            for (int j = 0; j < 8; ++j) acc[i][j] = 0.f;
        for (int kb = 0; kb < K_TOT; kb += KB) {
            __syncthreads();
#pragma unroll
            for (int r = 0; r < 4; ++r) {
                int f  = tid + 256 * r;
                int kk = f >> 5;
                int c4 = f & 31;
                float4 va = *reinterpret_cast<const float4*>(&L[(size_t)(kb + kk) * M_TOT + m0 + c4 * 4]);
                *reinterpret_cast<float4*>(&As[kk][c4 * 4]) = va;
                float4 vb = *reinterpret_cast<const float4*>(&R[(size_t)(kb + kk) * N_TOT + n0 + c4 * 4]);
                *reinterpret_cast<float4*>(&Bs[kk][c4 * 4]) = vb;
            }
            __syncthreads();
#pragma unroll 4
            for (int kk = 0; kk < KB; ++kk) {
                float4 a0 = *reinterpret_cast<const float4*>(&As[kk][ty * 4]);
                float4 a1 = *reinterpret_cast<const float4*>(&As[kk][64 + ty * 4]);
                float4 b0 = *reinterpret_cast<const float4*>(&Bs[kk][tx * 4]);
                float4 b1 = *reinterpret_cast<const float4*>(&Bs[kk][64 + tx * 4]);
                float a[8] = {a0.x, a0.y, a0.z, a0.w, a1.x, a1.y, a1.z, a1.w};
                float b[8] = {b0.x, b0.y, b0.z, b0.w, b1.x, b1.y, b1.z, b1.w};
#pragma unroll
                for (int i = 0; i < 8; ++i)
#pragma unroll
                    for (int j = 0; j < 8; ++j)
                        acc[i][j] = fmaf(a[i], b[j], acc[i][j]);
            }
        }
#pragma unroll
        for (int i = 0; i < 8; ++i)
#pragma unroll
            for (int jh = 0; jh < 2; ++jh)
#pragma unroll
                for (int jj = 0; jj < 4; ++jj) {
                    int n = n0 + jh * 64 + tx * 4 + jj;
                    float v = acc[i][jh * 4 + jj];
                    if (v > rbest[i]) { rbest[i] = v; ridx[i] = n; }
                }
    }
    __syncthreads();
    float (*redv)[BM] = reinterpret_cast<float(*)[BM]>(&As[0][0]);
    int   (*redi)[BM] = reinterpret_cast<int  (*)[BM]>(&Bs[0][0]);
#pragma unroll
    for (int i = 0; i < 8; ++i) {
        int row = (i >> 2) * 64 + ty * 4 + (i & 3);
        redv[tx][row] = rbest[i];
        redi[tx][row] = ridx[i];
    }
    __syncthreads();
    if (tid < BM) {
        float bv = NEG_INF; int bi = 0x7fffffff;
        for (int t = 0; t < 16; ++t) {
            float v  = redv[t][tid];
            int   ix = redi[t][tid];
            if (v > bv || (v == bv && ix < bi)) { bv = v; bi = ix; }
        }
        pbest[(size_t)s * M_TOT + m0 + tid] = bv;
        pidx [(size_t)s * M_TOT + m0 + tid] = bi;
    }
}

__global__ void finalize_parts_kernel(const float* __restrict__ pbest,
                                      const int* __restrict__ pidx,
                                      float* __restrict__ out, int nsplit) {
    int m = blockIdx.x * blockDim.x + threadIdx.x;
    if (m >= M_TOT) return;
    float bv = NEG_INF; int bi = 0x7fffffff;
    for (int s = 0; s < nsplit; ++s) {
        float v  = pbest[(size_t)s * M_TOT + m];
        int   ix = pidx [(size_t)s * M_TOT + m];
        if (v > bv || (v == bv && ix < bi)) { bv = v; bi = ix; }
    }
    int h = m / W_DIM, w = m % W_DIM;
    int i = bi / W_DIM, j = bi % W_DIM;
    out[m * 2 + 0] = (float)(w - SCALE * j);
    out[m * 2 + 1] = (float)(h - SCALE * i);
    out[2 * M_TOT + m] = bv;
}

extern "C" void kernel_launch(void* const* d_in, const int* in_sizes, int n_in,
                              void* d_out, int out_size, void* d_ws, size_t ws_size,
                              hipStream_t stream) {
    const float* L = (const float*)d_in[0];
    const float* R = (const float*)d_in[1];
    float* out = (float*)d_out;

    const size_t PKbytes = (size_t)M_TOT * KP * sizeof(_Float16);   // 9.44 MB
    const size_t need = 2 * PKbytes + (size_t)M_TOT * 8;            // ~19 MB
    if (ws_size >= need) {
        _Float16* Ls = (_Float16*)d_ws;
        _Float16* Rs = (_Float16*)((char*)d_ws + PKbytes);
        unsigned long long* keys = (unsigned long long*)((char*)d_ws + 2 * PKbytes);
        split_prep_kernel<<<dim3(384), dim3(256), 0, stream>>>(L, R, Ls, Rs);
        init_keys_kernel<<<dim3(48), dim3(256), 0, stream>>>(keys);
        mfma_corr_kernel<<<dim3((M_TOT / 128) * (N_TOT / 256)), dim3(256), 0, stream>>>(Ls, Rs, keys);
        finalize_keys_kernel<<<dim3(48), dim3(256), 0, stream>>>(keys, out);
    } else {
        int nsplit = 8;
        while (nsplit > 1 && (size_t)nsplit * M_TOT * 8 > ws_size) nsplit >>= 1;
        float* pbest = (float*)d_ws;
        int*   pidx  = (int*)((char*)d_ws + (size_t)nsplit * M_TOT * sizeof(float));
        corr_argmax_kernel<<<dim3((M_TOT / BM) * nsplit), dim3(256), 0, stream>>>(L, R, pbest, pidx, nsplit);
        finalize_parts_kernel<<<dim3((M_TOT + 255) / 256), dim3(256), 0, stream>>>(pbest, pidx, out, nsplit);
    }
}

// Round 5
// 254.192 us; speedup vs baseline: 2.4654x; 1.1094x over previous
//
#include <hip/hip_runtime.h>

// Problem constants: B=1, C=128, H=96, W=128
#define K_TOT 128
#define H_DIM 96
#define W_DIM 128
#define M_TOT (H_DIM * W_DIM)   // 12288
#define N_TOT (H_DIM * W_DIM)   // 12288
#define SCALE 4
#define NEG_INF (-3.402823e38f)

#define KP 384                  // folded K' = 3 x 128 sections
#define NCH 12                  // K' chunks of 32

typedef _Float16 f16x8 __attribute__((ext_vector_type(8)));
typedef float f32x16 __attribute__((ext_vector_type(16)));

// async global->LDS, 16B/lane; LDS dest = wave-uniform base + lane*16
#define ASYNC16(lds_ptr, g_ptr) \
  __builtin_amdgcn_global_load_lds( \
      (const __attribute__((address_space(1))) unsigned int*)(g_ptr), \
      (__attribute__((address_space(3))) unsigned int*)(lds_ptr), 16, 0, 0)

// ---------------------------------------------------------------------------
// Prep: fp32 [K][P] -> f16 triplet rows [P][384], plus fused keys-init.
//  x = h + l/64 with h=f16(x), l=f16((x-hf)*64)  (x-hf exact by Sterbenz)
//  L rows: [h | h/64 | l]   R rows: [h | l | h/64]
//  => dot(A',B') = h*h' + h*(y-h') + (x-h)*h'  (drop (x-h)(y-h') ~ 2^-22|xy|)
// ---------------------------------------------------------------------------
__global__ __launch_bounds__(256)
void split_prep_kernel(const float* __restrict__ L, const float* __restrict__ R,
                       _Float16* __restrict__ Ls, _Float16* __restrict__ Rs,
                       unsigned long long* __restrict__ keys) {
    const int t = threadIdx.x;
    if (blockIdx.x >= 384) {            // fused keys init (48 blocks)
        int m = (blockIdx.x - 384) * 256 + t;
        if (m < M_TOT) keys[m] = 0ull;
        return;
    }
    __shared__ __align__(16) _Float16 T[3][64][136];   // planes: 0=h, 1=l, 2=h/64
    const int isR = blockIdx.x >= 192;
    const int P0 = (blockIdx.x - (isR ? 192 : 0)) * 64;
    const float* src = isR ? R : L;
    _Float16* dst = isR ? Rs : Ls;

    const int p4 = (t & 15) * 4;
    const int k0 = t >> 4;
#pragma unroll
    for (int it = 0; it < 8; ++it) {
        const int k = k0 + it * 16;
        float4 v = *(const float4*)&src[(size_t)k * M_TOT + P0 + p4];
        float xs[4] = {v.x, v.y, v.z, v.w};
#pragma unroll
        for (int j = 0; j < 4; ++j) {
            _Float16 h = (_Float16)xs[j];
            float hf = (float)h;
            float r = xs[j] - hf;                    // exact
            T[0][p4 + j][k] = h;
            T[1][p4 + j][k] = (_Float16)(r * 64.0f);
            T[2][p4 + j][k] = (_Float16)(hf * 0.015625f);  // h/64 (exact exp shift)
        }
    }
    __syncthreads();
    // write out: 64 rows x 48 chunks of 16B (8 f16). sec0=h, then per-side order.
#pragma unroll
    for (int it = 0; it < 12; ++it) {
        const int cid = it * 256 + t;
        const int row = cid / 48;
        const int seg = cid % 48;
        const int sec = seg >> 4;       // 0,1,2
        const int sub = seg & 15;
        const int plane = (sec == 0) ? 0 : (isR ? sec : 3 - sec);
        float4 v = *(const float4*)&T[plane][row][sub * 8];
        *(float4*)&dst[(size_t)(P0 + row) * KP + seg * 8] = v;
    }
}

// ---------------------------------------------------------------------------
// Main: 128x256 tile per 4-wave block; wave-tile 64x128; mfma_f32_32x32x16_f16;
// K'=384 in 12 chunks of 32, double-buffered LDS with 1 barrier per chunk.
// LDS rows of 64B = 4 x 16B slots, slot XOR-swizzled by ((row>>1)&3);
// staging pre-swizzles the per-lane GLOBAL source (rule #21).
// Epilogue: ni-fold -> lane^16 fold -> LDS transpose [128][33] -> row scan
// -> one packed-u64 atomicMax per m.
// ---------------------------------------------------------------------------
__global__ __launch_bounds__(256, 3)
void mfma_corr_kernel(const _Float16* __restrict__ Ls, const _Float16* __restrict__ Rs,
                      unsigned long long* __restrict__ keys) {
    __shared__ __align__(16) char smem[49152];
    _Float16 (*As)[128 * 32] = (_Float16(*)[128 * 32])smem;              // 2 x 8KB
    _Float16 (*Bs)[256 * 32] = (_Float16(*)[256 * 32])(smem + 16384);    // 2 x 16KB

    const int tid  = threadIdx.x;
    const int lane = tid & 63;
    const int wid  = tid >> 6;      // 0..3
    const int wr   = wid >> 1;      // 0..1 : M 64-row slab
    const int wc   = wid & 1;       // 0..1 : N 128-col slab
    const int mt   = blockIdx.x % (M_TOT / 128);
    const int nt   = blockIdx.x / (M_TOT / 128);
    const int m0   = mt * 128;
    const int n0   = nt * 256;

    f32x16 acc[2][4];
#pragma unroll
    for (int mi = 0; mi < 2; ++mi)
#pragma unroll
        for (int ni = 0; ni < 4; ++ni) acc[mi][ni] = (f32x16)(0.0f);

    const int lr4  = lane >> 2;     // row within 16-row segment
    const int lsl  = lane & 3;      // physical slot
    const int col  = lane & 31;     // MFMA row/col lane index
    const int hi   = lane >> 5;     // k-half

    // stage one 32-f16 chunk of A(128 rows)+B(256 rows): 24 segs, 6 per wave
    auto stage = [&](int buf, int ch) {
#pragma unroll
        for (int i = 0; i < 6; ++i) {
            const int s  = wid * 6 + i;
            const int rl = (s < 8 ? s : s - 8) * 16 + lr4;
            const int ko = lsl ^ ((rl >> 1) & 3);       // pre-swizzled source slot
            if (s < 8) {
                ASYNC16((char*)&As[buf][0] + s * 1024,
                        Ls + (size_t)(m0 + rl) * KP + ch * 32 + ko * 8);
            } else {
                ASYNC16((char*)&Bs[buf][0] + (s - 8) * 1024,
                        Rs + (size_t)(n0 + rl) * KP + ch * 32 + ko * 8);
            }
        }
    };

    stage(0, 0);
    __syncthreads();
    int cur = 0;
    for (int ch = 0; ch < NCH; ++ch) {
        if (ch + 1 < NCH) stage(cur ^ 1, ch + 1);   // prefetch next chunk
#pragma unroll
        for (int kk = 0; kk < 2; ++kk) {            // two K=16 halves of the chunk
            f16x8 a[2], b[4];
#pragma unroll
            for (int mi = 0; mi < 2; ++mi) {
                const int rl = wr * 64 + mi * 32 + col;
                const int sl = (kk * 2 + hi) ^ ((rl >> 1) & 3);
                a[mi] = *(const f16x8*)((const char*)&As[cur][0] + rl * 64 + sl * 16);
            }
#pragma unroll
            for (int ni = 0; ni < 4; ++ni) {
                const int rl = wc * 128 + ni * 32 + col;
                const int sl = (kk * 2 + hi) ^ ((rl >> 1) & 3);
                b[ni] = *(const f16x8*)((const char*)&Bs[cur][0] + rl * 64 + sl * 16);
            }
#pragma unroll
            for (int mi = 0; mi < 2; ++mi)
#pragma unroll
                for (int ni = 0; ni < 4; ++ni)
                    acc[mi][ni] = __builtin_amdgcn_mfma_f32_32x32x16_f16(
                        a[mi], b[ni], acc[mi][ni], 0, 0, 0);
        }
        __syncthreads();   // drains vmcnt(0): next buffer staged; LDS reads done
        cur ^= 1;
    }

    // --- epilogue ---
    // C/D 32x32 layout: col = lane&31, row = (reg&3) + 8*(reg>>2) + 4*(lane>>5)
    // After the final barrier, As/Bs are dead -> reuse as [128][33] val/idx.
    float* vals = (float*)smem;                    // 128*33*4 = 16896 B
    int*   idxs = (int*)(smem + 16896);            // 128*33*4 = 16896 B
#pragma unroll
    for (int mi = 0; mi < 2; ++mi) {
#pragma unroll
        for (int reg = 0; reg < 16; ++reg) {
            float best = acc[mi][0][reg];
            int bni = 0;
#pragma unroll
            for (int ni = 1; ni < 4; ++ni) {       // ascending n => first-occurrence
                if (acc[mi][ni][reg] > best) { best = acc[mi][ni][reg]; bni = ni; }
            }
            int n = n0 + wc * 128 + bni * 32 + col;
            // fold col c with c+16 (lane^16; same hi, same rows)
            float ov = __shfl_xor(best, 16, 64);
            int   oi = __shfl_xor(n, 16, 64);
            if (ov > best || (ov == best && oi < n)) { best = ov; n = oi; }
            if ((lane & 16) == 0) {
                const int row = wr * 64 + mi * 32 + (reg & 3) + 8 * (reg >> 2) + 4 * hi;
                const int c   = wc * 16 + (lane & 15);
                vals[row * 33 + c] = best;
                idxs[row * 33 + c] = n;
            }
        }
    }
    __syncthreads();
    if (tid < 128) {
        float bv = vals[tid * 33 + 0]; int bi = idxs[tid * 33 + 0];
#pragma unroll
        for (int c = 1; c < 32; ++c) {
            float v = vals[tid * 33 + c]; int ix = idxs[tid * 33 + c];
            if (v > bv || (v == bv && ix < bi)) { bv = v; bi = ix; }
        }
        unsigned vb = __float_as_uint(bv);
        vb = (vb & 0x80000000u) ? ~vb : (vb | 0x80000000u);
        unsigned long long key = ((unsigned long long)vb << 32) | (unsigned)(~bi);
        atomicMax(&keys[m0 + tid], key);
    }
}

// decode keys -> flow + cost
__global__ void finalize_keys_kernel(const unsigned long long* __restrict__ keys,
                                     float* __restrict__ out) {
    int m = blockIdx.x * blockDim.x + threadIdx.x;
    if (m >= M_TOT) return;
    unsigned long long key = keys[m];
    unsigned hi = (unsigned)(key >> 32);
    unsigned bits = (hi & 0x80000000u) ? (hi & 0x7fffffffu) : ~hi;
    float v = __uint_as_float(bits);
    int idx = (int)(~(unsigned)(key & 0xffffffffu));
    int h = m / W_DIM, w = m % W_DIM;
    int i = idx / W_DIM, j = idx % W_DIM;
    out[m * 2 + 0] = (float)(w - SCALE * j);
    out[m * 2 + 1] = (float)(h - SCALE * i);
    out[2 * M_TOT + m] = v;
}

// ---------------------------------------------------------------------------
// Fallback fp32 VALU path in case ws_size is too small.
// ---------------------------------------------------------------------------
#define BM 128
#define BN 128
#define KB 32
__global__ __launch_bounds__(256)
void corr_argmax_kernel(const float* __restrict__ L, const float* __restrict__ R,
                        float* __restrict__ pbest, int* __restrict__ pidx,
                        int nsplit) {
    __shared__ float As[KB][BM];
    __shared__ float Bs[KB][BN];
    const int tid = threadIdx.x;
    const int mtiles = M_TOT / BM;
    const int mt = blockIdx.x % mtiles;
    const int s  = blockIdx.x / mtiles;
    const int m0 = mt * BM;
    const int ns = N_TOT / nsplit;
    const int ntiles = ns / BN;
    const int tx = tid & 15;
    const int ty = tid >> 4;
    float rbest[8]; int ridx[8];
#pragma unroll
    for (int i = 0; i < 8; ++i) { rbest[i] = NEG_INF; ridx[i] = 0; }
    for (int nt = 0; nt < ntiles; ++nt) {
        const int n0 = s * ns + nt * BN;
        float acc[8][8];
#pragma unroll
        for (int i = 0; i < 8; ++i)
#pragma unroll
            for (int j = 0; j < 8; ++j) acc[i][j] = 0.f;
        for (int kb = 0; kb < K_TOT; kb += KB) {
            __syncthreads();
#pragma unroll
            for (int r = 0; r < 4; ++r) {
                int f  = tid + 256 * r;
                int kk = f >> 5;
                int c4 = f & 31;
                float4 va = *reinterpret_cast<const float4*>(&L[(size_t)(kb + kk) * M_TOT + m0 + c4 * 4]);
                *reinterpret_cast<float4*>(&As[kk][c4 * 4]) = va;
                float4 vb = *reinterpret_cast<const float4*>(&R[(size_t)(kb + kk) * N_TOT + n0 + c4 * 4]);
                *reinterpret_cast<float4*>(&Bs[kk][c4 * 4]) = vb;
            }
            __syncthreads();
#pragma unroll 4
            for (int kk = 0; kk < KB; ++kk) {
                float4 a0 = *reinterpret_cast<const float4*>(&As[kk][ty * 4]);
                float4 a1 = *reinterpret_cast<const float4*>(&As[kk][64 + ty * 4]);
                float4 b0 = *reinterpret_cast<const float4*>(&Bs[kk][tx * 4]);
                float4 b1 = *reinterpret_cast<const float4*>(&Bs[kk][64 + tx * 4]);
                float a[8] = {a0.x, a0.y, a0.z, a0.w, a1.x, a1.y, a1.z, a1.w};
                float b[8] = {b0.x, b0.y, b0.z, b0.w, b1.x, b1.y, b1.z, b1.w};
#pragma unroll
                for (int i = 0; i < 8; ++i)
#pragma unroll
                    for (int j = 0; j < 8; ++j)
                        acc[i][j] = fmaf(a[i], b[j], acc[i][j]);
            }
        }
#pragma unroll
        for (int i = 0; i < 8; ++i)
#pragma unroll
            for (int jh = 0; jh < 2; ++jh)
#pragma unroll
                for (int jj = 0; jj < 4; ++jj) {
                    int n = n0 + jh * 64 + tx * 4 + jj;
                    float v = acc[i][jh * 4 + jj];
                    if (v > rbest[i]) { rbest[i] = v; ridx[i] = n; }
                }
    }
    __syncthreads();
    float (*redv)[BM] = reinterpret_cast<float(*)[BM]>(&As[0][0]);
    int   (*redi)[BM] = reinterpret_cast<int  (*)[BM]>(&Bs[0][0]);
#pragma unroll
    for (int i = 0; i < 8; ++i) {
        int row = (i >> 2) * 64 + ty * 4 + (i & 3);
        redv[tx][row] = rbest[i];
        redi[tx][row] = ridx[i];
    }
    __syncthreads();
    if (tid < BM) {
        float bv = NEG_INF; int bi = 0x7fffffff;
        for (int t = 0; t < 16; ++t) {
            float v  = redv[t][tid];
            int   ix = redi[t][tid];
            if (v > bv || (v == bv && ix < bi)) { bv = v; bi = ix; }
        }
        pbest[(size_t)s * M_TOT + m0 + tid] = bv;
        pidx [(size_t)s * M_TOT + m0 + tid] = bi;
    }
}

__global__ void finalize_parts_kernel(const float* __restrict__ pbest,
                                      const int* __restrict__ pidx,
                                      float* __restrict__ out, int nsplit) {
    int m = blockIdx.x * blockDim.x + threadIdx.x;
    if (m >= M_TOT) return;
    float bv = NEG_INF; int bi = 0x7fffffff;
    for (int s = 0; s < nsplit; ++s) {
        float v  = pbest[(size_t)s * M_TOT + m];
        int   ix = pidx [(size_t)s * M_TOT + m];
        if (v > bv || (v == bv && ix < bi)) { bv = v; bi = ix; }
    }
    int h = m / W_DIM, w = m % W_DIM;
    int i = bi / W_DIM, j = bi % W_DIM;
    out[m * 2 + 0] = (float)(w - SCALE * j);
    out[m * 2 + 1] = (float)(h - SCALE * i);
    out[2 * M_TOT + m] = bv;
}

extern "C" void kernel_launch(void* const* d_in, const int* in_sizes, int n_in,
                              void* d_out, int out_size, void* d_ws, size_t ws_size,
                              hipStream_t stream) {
    const float* L = (const float*)d_in[0];
    const float* R = (const float*)d_in[1];
    float* out = (float*)d_out;

    const size_t PKbytes = (size_t)M_TOT * KP * sizeof(_Float16);   // 9.44 MB
    const size_t need = 2 * PKbytes + (size_t)M_TOT * 8;            // ~19 MB
    if (ws_size >= need) {
        _Float16* Ls = (_Float16*)d_ws;
        _Float16* Rs = (_Float16*)((char*)d_ws + PKbytes);
        unsigned long long* keys = (unsigned long long*)((char*)d_ws + 2 * PKbytes);
        split_prep_kernel<<<dim3(432), dim3(256), 0, stream>>>(L, R, Ls, Rs, keys);
        mfma_corr_kernel<<<dim3((M_TOT / 128) * (N_TOT / 256)), dim3(256), 0, stream>>>(Ls, Rs, keys);
        finalize_keys_kernel<<<dim3(48), dim3(256), 0, stream>>>(keys, out);
    } else {
        int nsplit = 8;
        while (nsplit > 1 && (size_t)nsplit * M_TOT * 8 > ws_size) nsplit >>= 1;
        float* pbest = (float*)d_ws;
        int*   pidx  = (int*)((char*)d_ws + (size_t)nsplit * M_TOT * sizeof(float));
        corr_argmax_kernel<<<dim3((M_TOT / BM) * nsplit), dim3(256), 0, stream>>>(L, R, pbest, pidx, nsplit);
        finalize_parts_kernel<<<dim3((M_TOT + 255) / 256), dim3(256), 0, stream>>>(pbest, pidx, out, nsplit);
    }
}